// Round 4
// baseline (4189.596 us; speedup 1.0000x reference)
//
#include <hip/hip_runtime.h>

#define NROWS 16384
#define DIN   1024
#define DH    4096
#define DZ    256
#define KCB   4096

typedef _Float16 f16x8 __attribute__((ext_vector_type(8)));
typedef _Float16 f16x4 __attribute__((ext_vector_type(4)));
typedef float    f32x4 __attribute__((ext_vector_type(4)));

#define INV4096 2.44140625e-4f
#define F16_MIN_NORMAL 6.103515625e-05f

struct Split { _Float16 h, l; };

// Split v into h + l/4096 with h, l normal-or-zero f16 (denormal-safe).
__device__ inline Split splitf(float v) {
    _Float16 hh = (_Float16)v;
    float hf = (float)hh;
    if (fabsf(hf) < F16_MIN_NORMAL) { hh = (_Float16)0.0f; hf = 0.0f; }
    Split s;
    s.h = hh;
    s.l = (_Float16)((v - hf) * 4096.0f);
    return s;
}

__device__ inline void gload_lds16(const void* g, void* l) {
    __builtin_amdgcn_global_load_lds(
        (const __attribute__((address_space(1))) void*)g,
        (__attribute__((address_space(3))) void*)l, 16, 0, 0);
}

// ---------------------------------------------------------------------------
__global__ void k_init_best(unsigned long long* best) {
    int i = blockIdx.x * 256 + threadIdx.x;
    if (i < NROWS) best[i] = 0xFFFFFFFFFFFFFFFFULL;
}

// Element-wise fp32 -> split f16 pair. n multiple of 1024.
__global__ void k_esplit(const float* __restrict__ X, _Float16* __restrict__ H,
                         _Float16* __restrict__ L, size_t n) {
    size_t i = ((size_t)blockIdx.x * 256 + threadIdx.x) * 4;
    if (i >= n) return;
    float4 v = *(const float4*)(X + i);
    f16x4 hv, lv;
    Split s0 = splitf(v.x), s1 = splitf(v.y), s2 = splitf(v.z), s3 = splitf(v.w);
    hv[0] = s0.h; hv[1] = s1.h; hv[2] = s2.h; hv[3] = s3.h;
    lv[0] = s0.l; lv[1] = s1.l; lv[2] = s2.l; lv[3] = s3.l;
    *(f16x4*)(H + i) = hv;
    *(f16x4*)(L + i) = lv;
}

// Transpose + split: B[K][N] fp32 -> Th/Tl [N][K] f16. K,N multiples of 32.
__global__ void k_tsplit(const float* __restrict__ B, _Float16* __restrict__ Th,
                         _Float16* __restrict__ Tl, int K, int N) {
    __shared__ float tile[32][33];
    const int k0 = blockIdx.x * 32, n0 = blockIdx.y * 32;
    const int tx = threadIdx.x, ty = threadIdx.y;   // block (32,8)
#pragma unroll
    for (int i = 0; i < 4; i++)
        tile[ty + i * 8][tx] = B[(size_t)(k0 + ty + i * 8) * N + n0 + tx];
    __syncthreads();
#pragma unroll
    for (int i = 0; i < 4; i++) {
        float v = tile[tx][ty + i * 8];
        Split s = splitf(v);
        size_t o = (size_t)(n0 + ty + i * 8) * K + k0 + tx;
        Th[o] = s.h; Tl[o] = s.l;
    }
}

// ---------------------------------------------------------------------------
// Split-precision f16 MFMA GEMM, 128x128 tile, A-stream direct global->reg.
// C = A[M,K] @ Bt[N,K]^T (+bias).  A as Ah/Al [M][K], B as Bh/Bl [N][K],
// value = h + l/4096.  BK=32, 4 waves (2Mx2N), per-wave 64x64.
//
// LDS-pipe decongestion: only B goes through LDS (double-buffered 32 KB,
// staged one K-tile ahead via global_load_lds, counted by the compiler's
// vmcnt).  A fragments are loaded straight from global into the MFMA
// operand registers (16 B/lane at A[row][k+quad*8] -- naturally the frag
// layout, no swizzle needed, L2-resident).  This halves LDS traffic so the
// LDS pipe (~1120 cyc/CU per tile-pair) no longer rivals the MFMA pipe
// (~1980 cyc/CU) -- even a phase-locked 2-block schedule improves.
// B LDS is XOR-swizzled: phys kslot = q ^ ((row>>1)&3); global_load_lds
// writes linearly so the inverse permutation is applied to the per-lane
// GLOBAL source address (both-sides-or-neither rule).
// XCD swizzle: gridDim.x==32 for every use; dispatch id % 8 = XCD, so
// bx = (x&7)*4 + x>>3 gives each XCD 4 contiguous B-panel columns (B-tile
// L2 locality; bijective for x in [0,32)).
// MODE 0: Ch/Cl = split(relu(C+bias));  MODE 1: split(C+bias)
// MODE 3: distance epilogue: d = Z2[m] + C2[n] - 2*C; packed atomicMin(best)
template <int MODE>
__global__ __launch_bounds__(256, 2)
void k_gemm8(const _Float16* __restrict__ Ah, const _Float16* __restrict__ Al,
             const _Float16* __restrict__ Bh, const _Float16* __restrict__ Bl,
             const float* __restrict__ bias,
             _Float16* __restrict__ Ch, _Float16* __restrict__ Cl,
             const float* __restrict__ Z2, const float* __restrict__ C2,
             unsigned long long* __restrict__ best,
             int N, int K) {
    constexpr int BUF = 8192;                  // f16 per buffer = 16 KB
    // per buffer: Bh @0 (128x32), Bl @4096
    __shared__ __align__(16) _Float16 lds[2 * BUF];   // 32 KB

    const int tid  = threadIdx.x;
    const int w    = tid >> 6;
    const int l    = tid & 63;
    const int wm   = w >> 1, wn = w & 1;       // 2Mx2N wave grid
    const int quad = l >> 4, lcol = l & 15;

    // XCD-aware bx remap (bijective on [0,32); dispatch linear id % 8 = XCD)
    const int bx = ((int)blockIdx.x & 7) * 4 + ((int)blockIdx.x >> 3);
    const long m0 = (long)blockIdx.y * 128;
    const long n0 = (long)bx * 128;

    // Swizzled per-lane B read offset (f16 units) within a matrix segment.
    // row = rb + lcol (rb % 16 == 0) -> (row>>1)&3 == (l>>1)&3.
    const int lidx = lcol * 32 + ((quad ^ ((l >> 1) & 3)) * 8);

    // A direct-to-register pointers: lane covers A[m0+wm*64+fi*16+lcol]
    // [k0 + quad*8 .. +8] (16 B).  No swizzle (registers, not LDS).
    const int aRow = wm * 64 + lcol;
    const _Float16* pAh = Ah + (size_t)(m0 + aRow) * K + quad * 8;
    const _Float16* pAl = Al + (size_t)(m0 + aRow) * K + quad * 8;

    // B staging: wave w stages rows [w*32, w*32+32) of Bh and Bl (4 x
    // global_load_lds of 1 KB).  Lane covers 16 B: row-in-seg = l>>2, phys
    // k-slot = l&3, logical k-slot = (l&3)^((l>>3)&3) (inverse swizzle;
    // (row>>1)&3 == (l>>3)&3 since row = seg*16 + (l>>2)).
    const int grow = l >> 2;
    const int kq8  = (((l & 3) ^ ((l >> 3) & 3)) << 3);
    const _Float16* gBh = Bh + (size_t)(n0 + w * 32 + grow) * K + kq8;
    const _Float16* gBl = Bl + (size_t)(n0 + w * 32 + grow) * K + kq8;
    const int woff = w * 1024;                 // wave's 32-row slice (f16)

    f32x4 acc_h[4][4], acc_x[4][4];
#pragma unroll
    for (int i = 0; i < 4; i++)
#pragma unroll
        for (int j = 0; j < 4; j++) {
            acc_h[i][j] = (f32x4){0.f, 0.f, 0.f, 0.f};
            acc_x[i][j] = (f32x4){0.f, 0.f, 0.f, 0.f};
        }

    const int NT = K >> 5;                     // K-tiles (>= 8 for all uses)

#define STAGEB(bi, koff) do { \
        _Float16* d = lds + (bi) * BUF + woff; \
        gload_lds16(gBh + (koff),                 d);          \
        gload_lds16(gBh + (koff) + (size_t)16*K,  d + 512);    \
        gload_lds16(gBl + (koff),                 d + 4096);   \
        gload_lds16(gBl + (koff) + (size_t)16*K,  d + 4608); } while (0)

    // ---- prologue: stage tile 0 -> buf0 ----
    STAGEB(0, 0);
    asm volatile("s_waitcnt vmcnt(0)" ::: "memory");
    __builtin_amdgcn_s_barrier();

#define LDB8(fj) do { \
        fb_h[fj] = *(const f16x8*)(sBh_ + (wn * 64 + (fj) * 16) * 32 + lidx); \
        fb_l[fj] = *(const f16x8*)(sBl_ + (wn * 64 + (fj) * 16) * 32 + lidx); } while (0)
#define MM3(fi, fj) do { \
        acc_h[fi][fj] = __builtin_amdgcn_mfma_f32_16x16x32_f16(fa_h[fi], fb_h[fj], acc_h[fi][fj], 0, 0, 0); \
        acc_x[fi][fj] = __builtin_amdgcn_mfma_f32_16x16x32_f16(fa_h[fi], fb_l[fj], acc_x[fi][fj], 0, 0, 0); \
        acc_x[fi][fj] = __builtin_amdgcn_mfma_f32_16x16x32_f16(fa_l[fi], fb_h[fj], acc_x[fi][fj], 0, 0, 0); } while (0)

    for (int t = 0; t < NT; ++t) {
        const _Float16* buf = lds + (t & 1) * BUF;
        const _Float16* sBh_ = buf;
        const _Float16* sBl_ = buf + 4096;
        const bool st = (t + 1) < NT;
        const int k0 = t * 32;
        f16x8 fa_h[4], fa_l[4], fb_h[4], fb_l[4];

        // A frags for THIS tile: direct global->reg (compiler inserts the
        // counted vmcnt before first MFMA use; staging stays in flight).
#pragma unroll
        for (int fi = 0; fi < 4; fi++) {
            fa_h[fi] = *(const f16x8*)(pAh + (size_t)fi * 16 * K + k0);
            fa_l[fi] = *(const f16x8*)(pAl + (size_t)fi * 16 * K + k0);
        }

        // Stage tile t+1's B (4 x global_load_lds/wave, counted at boundary)
        if (st) STAGEB((t + 1) & 1, k0 + 32);

        // B frag reads (8 x ds_read_b128/wave, counted lgkm before MFMA)
        LDB8(0); LDB8(1); LDB8(2); LDB8(3);

        __builtin_amdgcn_s_setprio(1);
        MM3(0, 0); MM3(0, 1); MM3(1, 0); MM3(1, 1);
        MM3(0, 2); MM3(0, 3); MM3(1, 2); MM3(1, 3);
        MM3(2, 0); MM3(2, 1); MM3(3, 0); MM3(3, 1);
        MM3(2, 2); MM3(2, 3); MM3(3, 2); MM3(3, 3);
        __builtin_amdgcn_s_setprio(0);

        // Boundary: tile t+1's B staging (issued a full MFMA cluster ago)
        // must be resident past this barrier.  A loads already drained.
        if (st) asm volatile("s_waitcnt vmcnt(0)" ::: "memory");
        __builtin_amdgcn_s_barrier();
    }
#undef STAGEB
#undef LDB8
#undef MM3

    if (MODE != 3) {
#pragma unroll
        for (int fj = 0; fj < 4; fj++) {
            const long col = n0 + wn * 64 + fj * 16 + lcol;
            const float bv = bias[col];
#pragma unroll
            for (int fi = 0; fi < 4; fi++) {
#pragma unroll
                for (int r = 0; r < 4; r++) {
                    const long row = m0 + wm * 64 + fi * 16 + quad * 4 + r;
                    float v = (acc_h[fi][fj][r] + INV4096 * acc_x[fi][fj][r]) + bv;
                    if (MODE == 0) v = fmaxf(v, 0.0f);
                    Split s = splitf(v);
                    const size_t o = (size_t)row * N + col;
                    Ch[o] = s.h; Cl[o] = s.l;
                }
            }
        }
    } else {
        float cc2[4];
#pragma unroll
        for (int fj = 0; fj < 4; fj++)
            cc2[fj] = C2[n0 + wn * 64 + fj * 16 + lcol];
#pragma unroll
        for (int fi = 0; fi < 4; fi++) {
#pragma unroll
            for (int r = 0; r < 4; r++) {
                const long row = m0 + wm * 64 + fi * 16 + quad * 4 + r;
                const float zz = Z2[row];
                float dmin = 3.4e38f; int didx = 0x7FFFFFFF;
#pragma unroll
                for (int fj = 0; fj < 4; fj++) {
                    float accv = acc_h[fi][fj][r] + INV4096 * acc_x[fi][fj][r];
                    int col = (int)(n0 + wn * 64 + fj * 16 + lcol);
                    float d = (zz + cc2[fj]) - 2.0f * accv;
                    if (d < dmin || (d == dmin && col < didx)) { dmin = d; didx = col; }
                }
#pragma unroll
                for (int off = 1; off < 16; off <<= 1) {
                    float ov = __shfl_xor(dmin, off, 64);
                    int   oi = __shfl_xor(didx, off, 64);
                    if (ov < dmin || (ov == dmin && oi < didx)) { dmin = ov; didx = oi; }
                }
                if (lcol == 0) {
                    unsigned long long pk =
                        ((unsigned long long)__float_as_uint(dmin) << 32) |
                        (unsigned long long)(unsigned)didx;
                    atomicMin(best + row, pk);
                }
            }
        }
    }
}

// ---------------------------------------------------------------------------
// Legacy 2-barrier split GEMM — kept for MODE 2 (W3: N=256, needs the small
// BM=64 tiling for grid occupancy).
template <int MODE, int MFRAGS>
__global__ __launch_bounds__(256, 2)
void k_gemm_split(const _Float16* __restrict__ Ah, const _Float16* __restrict__ Al,
                  const _Float16* __restrict__ Bh, const _Float16* __restrict__ Bl,
                  const float* __restrict__ bias,
                  _Float16* __restrict__ Ch, _Float16* __restrict__ Cl,
                  float* __restrict__ Cf,
                  const float* __restrict__ Z2, const float* __restrict__ C2,
                  unsigned long long* __restrict__ best,
                  int M, int N, int K) {
    constexpr int BM = MFRAGS * 32;               // 128 or 64
    __shared__ __align__(16) _Float16 sAh[BM * 32];
    __shared__ __align__(16) _Float16 sAl[BM * 32];
    __shared__ __align__(16) _Float16 sBh[128 * 32];
    __shared__ __align__(16) _Float16 sBl[128 * 32];

    const int tid  = threadIdx.x;
    const int w    = tid >> 6;
    const int l    = tid & 63;
    const int wm   = w >> 1, wn = w & 1;
    const int quad = l >> 4, lcol = l & 15;
    const long m0 = (long)blockIdx.y * BM;
    const long n0 = (long)blockIdx.x * 128;

    const _Float16* gsrc; _Float16* ldst; long rbase; int nld;
    if      (w == 0) { gsrc = Ah; ldst = sAh; rbase = m0; nld = BM / 16; }
    else if (w == 1) { gsrc = Al; ldst = sAl; rbase = m0; nld = BM / 16; }
    else if (w == 2) { gsrc = Bh; ldst = sBh; rbase = n0; nld = 8; }
    else             { gsrc = Bl; ldst = sBl; rbase = n0; nld = 8; }
    const _Float16* gbase = gsrc + (rbase + (l >> 2)) * (size_t)K + (l & 3) * 8;

    f32x4 acc_h[MFRAGS][4], acc_x[MFRAGS][4];
#pragma unroll
    for (int i = 0; i < MFRAGS; i++)
#pragma unroll
        for (int j = 0; j < 4; j++) {
            acc_h[i][j] = (f32x4){0.f, 0.f, 0.f, 0.f};
            acc_x[i][j] = (f32x4){0.f, 0.f, 0.f, 0.f};
        }

    for (int k0 = 0; k0 < K; k0 += 32) {
        for (int u = 0; u < nld; u++)
            gload_lds16(gbase + k0 + (size_t)u * 16 * K, ldst + u * 16 * 32);
        __syncthreads();

        f16x8 fa_h[MFRAGS], fa_l[MFRAGS], fb_h[4], fb_l[4];
#pragma unroll
        for (int fi = 0; fi < MFRAGS; fi++) {
            const int o = (wm * (MFRAGS * 16) + fi * 16 + lcol) * 32 + quad * 8;
            fa_h[fi] = *(const f16x8*)(sAh + o);
            fa_l[fi] = *(const f16x8*)(sAl + o);
        }
#pragma unroll
        for (int fj = 0; fj < 4; fj++) {
            const int o = (wn * 64 + fj * 16 + lcol) * 32 + quad * 8;
            fb_h[fj] = *(const f16x8*)(sBh + o);
            fb_l[fj] = *(const f16x8*)(sBl + o);
        }
#pragma unroll
        for (int fi = 0; fi < MFRAGS; fi++)
#pragma unroll
            for (int fj = 0; fj < 4; fj++) {
                acc_h[fi][fj] = __builtin_amdgcn_mfma_f32_16x16x32_f16(
                    fa_h[fi], fb_h[fj], acc_h[fi][fj], 0, 0, 0);
                acc_x[fi][fj] = __builtin_amdgcn_mfma_f32_16x16x32_f16(
                    fa_h[fi], fb_l[fj], acc_x[fi][fj], 0, 0, 0);
                acc_x[fi][fj] = __builtin_amdgcn_mfma_f32_16x16x32_f16(
                    fa_l[fi], fb_h[fj], acc_x[fi][fj], 0, 0, 0);
            }
        __syncthreads();
    }

    if (MODE != 3) {
#pragma unroll
        for (int fj = 0; fj < 4; fj++) {
            const long col = n0 + wn * 64 + fj * 16 + lcol;
            const float bv = bias[col];
#pragma unroll
            for (int fi = 0; fi < MFRAGS; fi++) {
#pragma unroll
                for (int r = 0; r < 4; r++) {
                    const long row = m0 + wm * (MFRAGS * 16) + fi * 16 + quad * 4 + r;
                    float v = (acc_h[fi][fj][r] + INV4096 * acc_x[fi][fj][r]) + bv;
                    if (MODE == 0) v = fmaxf(v, 0.0f);
                    Split s = splitf(v);
                    const size_t o = (size_t)row * N + col;
                    Ch[o] = s.h; Cl[o] = s.l;
                    if (MODE == 2) Cf[o] = v;
                }
            }
        }
    } else {
        float cc2[4];
#pragma unroll
        for (int fj = 0; fj < 4; fj++)
            cc2[fj] = C2[n0 + wn * 64 + fj * 16 + lcol];
#pragma unroll
        for (int fi = 0; fi < MFRAGS; fi++) {
#pragma unroll
            for (int r = 0; r < 4; r++) {
                const long row = m0 + wm * (MFRAGS * 16) + fi * 16 + quad * 4 + r;
                const float zz = Z2[row];
                float dmin = 3.4e38f; int didx = 0x7FFFFFFF;
#pragma unroll
                for (int fj = 0; fj < 4; fj++) {
                    float accv = acc_h[fi][fj][r] + INV4096 * acc_x[fi][fj][r];
                    int col = (int)(n0 + wn * 64 + fj * 16 + lcol);
                    float d = (zz + cc2[fj]) - 2.0f * accv;
                    if (d < dmin || (d == dmin && col < didx)) { dmin = d; didx = col; }
                }
#pragma unroll
                for (int off = 1; off < 16; off <<= 1) {
                    float ov = __shfl_xor(dmin, off, 64);
                    int   oi = __shfl_xor(didx, off, 64);
                    if (ov < dmin || (ov == dmin && oi < didx)) { dmin = ov; didx = oi; }
                }
                if (lcol == 0) {
                    unsigned long long pk =
                        ((unsigned long long)__float_as_uint(dmin) << 32) |
                        (unsigned long long)(unsigned)didx;
                    atomicMin(best + row, pk);
                }
            }
        }
    }
}

// ---------------------------------------------------------------------------
__global__ void k_row_sq_norms(const float* __restrict__ X, float* __restrict__ out,
                               int ncols, int nrows) {
    const int wave = threadIdx.x >> 6;
    const int lane = threadIdx.x & 63;
    const long row = (long)blockIdx.x * 4 + wave;
    if (row >= nrows) return;
    const float* p = X + row * (long)ncols;
    float s = 0.0f;
    for (int c = lane * 4; c < ncols; c += 256) {
        float4 v = *(const float4*)(p + c);
        s += v.x * v.x + v.y * v.y + v.z * v.z + v.w * v.w;
    }
#pragma unroll
    for (int off = 32; off > 0; off >>= 1) s += __shfl_down(s, off, 64);
    if (lane == 0) out[row] = s;
}

__global__ void k_loss(const unsigned long long* __restrict__ best,
                       float* __restrict__ out) {
    __shared__ float red[256];
    float s = 0.0f;
    for (int i = threadIdx.x; i < NROWS; i += 256)
        s += __uint_as_float((unsigned)(best[i] >> 32));
    red[threadIdx.x] = s;
    __syncthreads();
    for (int st = 128; st > 0; st >>= 1) {
        if (threadIdx.x < st) red[threadIdx.x] += red[threadIdx.x + st];
        __syncthreads();
    }
    if (threadIdx.x == 0) out[(size_t)NROWS * DZ] = 2.0f * red[0];
}

__global__ void k_output(const float* __restrict__ CB,
                         const unsigned long long* __restrict__ best,
                         float* __restrict__ out) {
    const long n = blockIdx.x;
    const int t = threadIdx.x;      // 64 threads
    const int wd = (int)(unsigned)(best[n] & 0xFFFFFFFFULL);
    float4 v = *(const float4*)(CB + (size_t)wd * DZ + t * 4);
    *(float4*)(out + n * (size_t)DZ + t * 4) = v;
}

// ---------------------------------------------------------------------------
extern "C" void kernel_launch(void* const* d_in, const int* in_sizes, int n_in,
                              void* d_out, int out_size, void* d_ws, size_t ws_size,
                              hipStream_t stream) {
    const float* x  = (const float*)d_in[0];
    const float* W1 = (const float*)d_in[1];
    const float* b1 = (const float*)d_in[2];
    const float* W2 = (const float*)d_in[3];
    const float* b2 = (const float*)d_in[4];
    const float* W3 = (const float*)d_in[5];
    const float* b3 = (const float*)d_in[6];
    const float* cb = (const float*)d_in[7];
    float* out = (float*)d_out;

    // ---- workspace carve-up (bytes, 256-aligned) ----
    char* base = (char*)d_ws;
    size_t off = 0;
    auto alloc = [&](size_t bytes) -> void* {
        void* p = base + off;
        off = (off + bytes + 255) & ~(size_t)255;
        return p;
    };
    // fixed region (~120 MB): weights, codebook, z, norms, best
    _Float16* W1tH = (_Float16*)alloc((size_t)DH * DIN * 2);
    _Float16* W1tL = (_Float16*)alloc((size_t)DH * DIN * 2);
    _Float16* W2tH = (_Float16*)alloc((size_t)DH * DH * 2);
    _Float16* W2tL = (_Float16*)alloc((size_t)DH * DH * 2);
    _Float16* W3tH = (_Float16*)alloc((size_t)DZ * DH * 2);
    _Float16* W3tL = (_Float16*)alloc((size_t)DZ * DH * 2);
    _Float16* cbH  = (_Float16*)alloc((size_t)KCB * DZ * 2);
    _Float16* cbL  = (_Float16*)alloc((size_t)KCB * DZ * 2);
    _Float16* zH   = (_Float16*)alloc((size_t)NROWS * DZ * 2);
    _Float16* zL   = (_Float16*)alloc((size_t)NROWS * DZ * 2);
    float*    zF   = (float*)alloc((size_t)NROWS * DZ * 4);
    float*    z2   = (float*)alloc((size_t)NROWS * 4);
    float*    c2   = (float*)alloc((size_t)KCB * 4);
    unsigned long long* best = (unsigned long long*)alloc((size_t)NROWS * 8);

    // chunk buffers: x split (4 KB/row) + h1 split (16 KB/row) + h2 split (16 KB/row)
    size_t rem = (ws_size > off) ? (ws_size - off) : 0;
    size_t rc = rem / ((size_t)DIN * 2 * 2 + (size_t)DH * 2 * 4);
    rc = (rc / 256) * 256;
    if (rc > NROWS) rc = NROWS;
    if (rc < 256)   rc = 256;
    _Float16* xcH = (_Float16*)alloc((size_t)rc * DIN * 2);
    _Float16* xcL = (_Float16*)alloc((size_t)rc * DIN * 2);
    _Float16* h1H = (_Float16*)alloc((size_t)rc * DH * 2);
    _Float16* h1L = (_Float16*)alloc((size_t)rc * DH * 2);
    _Float16* h2H = (_Float16*)alloc((size_t)rc * DH * 2);
    _Float16* h2L = (_Float16*)alloc((size_t)rc * DH * 2);

    // ---- one-time conversions ----
    k_init_best<<<(NROWS + 255) / 256, 256, 0, stream>>>(best);
    k_esplit<<<(unsigned)((size_t)KCB * DZ / 1024), 256, 0, stream>>>(
        cb, cbH, cbL, (size_t)KCB * DZ);
    k_tsplit<<<dim3(DIN / 32, DH / 32), dim3(32, 8), 0, stream>>>(W1, W1tH, W1tL, DIN, DH);
    k_tsplit<<<dim3(DH / 32, DH / 32),  dim3(32, 8), 0, stream>>>(W2, W2tH, W2tL, DH, DH);
    k_tsplit<<<dim3(DH / 32, DZ / 32),  dim3(32, 8), 0, stream>>>(W3, W3tH, W3tL, DH, DZ);

    // ---- MLP (chunked over rows; rows always a multiple of 256) ----
    for (size_t r0 = 0; r0 < NROWS; r0 += rc) {
        size_t rows = NROWS - r0;
        if (rows > rc) rows = rc;
        // x chunk -> split f16
        k_esplit<<<(unsigned)(rows * DIN / 1024), 256, 0, stream>>>(
            x + r0 * DIN, xcH, xcL, rows * DIN);
        // h1 = relu(x @ W1 + b1)
        k_gemm8<0><<<dim3(DH / 128, rows / 128), 256, 0, stream>>>(
            xcH, xcL, W1tH, W1tL, b1, h1H, h1L,
            nullptr, nullptr, nullptr, DH, DIN);
        // h2 = h1 @ W2 + b2
        k_gemm8<1><<<dim3(DH / 128, rows / 128), 256, 0, stream>>>(
            h1H, h1L, W2tH, W2tL, b2, h2H, h2L,
            nullptr, nullptr, nullptr, DH, DH);
        // z = h2 @ W3 + b3  (N=256 -> keep BM=64 legacy kernel for grid size)
        k_gemm_split<2, 2><<<dim3(DZ / 128, rows / 64), 256, 0, stream>>>(
            h2H, h2L, W3tH, W3tL, b3,
            zH + r0 * DZ, zL + r0 * DZ, zF + r0 * DZ,
            nullptr, nullptr, nullptr, (int)rows, DZ, DH);
    }

    // ---- norms + distance/argmin + outputs ----
    k_row_sq_norms<<<NROWS / 4, 256, 0, stream>>>(zF, z2, DZ, NROWS);
    k_row_sq_norms<<<KCB / 4, 256, 0, stream>>>(cb, c2, DZ, KCB);

    // distance + argmin  [K=256 -> NT=8]
    k_gemm8<3><<<dim3(KCB / 128, NROWS / 128), 256, 0, stream>>>(
        zH, zL, cbH, cbL, nullptr, nullptr, nullptr,
        z2, c2, best, KCB, DZ);

    k_loss<<<1, 256, 0, stream>>>(best, out);
    k_output<<<NROWS, 64, 0, stream>>>(cb, best, out);
}

// Round 6
// 2652.407 us; speedup vs baseline: 1.5795x; 1.5795x over previous
//
#include <hip/hip_runtime.h>

#define NROWS 16384
#define DIN   1024
#define DH    4096
#define DZ    256
#define KCB   4096
#define KSPLIT 8

typedef _Float16 f16x8 __attribute__((ext_vector_type(8)));
typedef _Float16 f16x4 __attribute__((ext_vector_type(4)));
typedef float    f32x4 __attribute__((ext_vector_type(4)));

#define INV4096 2.44140625e-4f
#define F16_MIN_NORMAL 6.103515625e-05f

struct Split { _Float16 h, l; };

// Split v into h + l/4096 with h, l normal-or-zero f16 (denormal-safe).
__device__ inline Split splitf(float v) {
    _Float16 hh = (_Float16)v;
    float hf = (float)hh;
    if (fabsf(hf) < F16_MIN_NORMAL) { hh = (_Float16)0.0f; hf = 0.0f; }
    Split s;
    s.h = hh;
    s.l = (_Float16)((v - hf) * 4096.0f);
    return s;
}

__device__ inline void gload_lds16(const void* g, void* l) {
    __builtin_amdgcn_global_load_lds(
        (const __attribute__((address_space(1))) void*)g,
        (__attribute__((address_space(3))) void*)l, 16, 0, 0);
}

// ---------------------------------------------------------------------------
__global__ void k_init_best(unsigned long long* best) {
    int i = blockIdx.x * 256 + threadIdx.x;
    if (i < NROWS) best[i] = 0xFFFFFFFFFFFFFFFFULL;
}

// Element-wise fp32 -> split f16 pair (residual form). n multiple of 1024.
__global__ void k_esplit(const float* __restrict__ X, _Float16* __restrict__ H,
                         _Float16* __restrict__ L, size_t n) {
    size_t i = ((size_t)blockIdx.x * 256 + threadIdx.x) * 4;
    if (i >= n) return;
    float4 v = *(const float4*)(X + i);
    f16x4 hv, lv;
    Split s0 = splitf(v.x), s1 = splitf(v.y), s2 = splitf(v.z), s3 = splitf(v.w);
    hv[0] = s0.h; hv[1] = s1.h; hv[2] = s2.h; hv[3] = s3.h;
    lv[0] = s0.l; lv[1] = s1.l; lv[2] = s2.l; lv[3] = s3.l;
    *(f16x4*)(H + i) = hv;
    *(f16x4*)(L + i) = lv;
}

// Transpose + split: B[K][N] fp32 -> Th/Tl [N][K] f16. K,N multiples of 32.
__global__ void k_tsplit(const float* __restrict__ B, _Float16* __restrict__ Th,
                         _Float16* __restrict__ Tl, int K, int N) {
    __shared__ float tile[32][33];
    const int k0 = blockIdx.x * 32, n0 = blockIdx.y * 32;
    const int tx = threadIdx.x, ty = threadIdx.y;   // block (32,8)
#pragma unroll
    for (int i = 0; i < 4; i++)
        tile[ty + i * 8][tx] = B[(size_t)(k0 + ty + i * 8) * N + n0 + tx];
    __syncthreads();
#pragma unroll
    for (int i = 0; i < 4; i++) {
        float v = tile[tx][ty + i * 8];
        Split s = splitf(v);
        size_t o = (size_t)(n0 + ty + i * 8) * K + k0 + tx;
        Th[o] = s.h; Tl[o] = s.l;
    }
}

// ---------------------------------------------------------------------------
// Split-precision f16 MFMA GEMM (3-stream), single-barrier-per-K-tile
// pipeline -- the round-3-verified structure: 128x128 tile, BK=32, 4 waves
// (2Mx2N), per-wave 64x64; double-buffered LDS (64 KB -> 2 blocks/CU)
// staged 1 tile ahead; one s_barrier per K-tile; 16 ds_read_b128 + 48 MFMA
// in one basic block (compiler emits counted lgkmcnt).  LDS XOR-swizzled:
// phys kslot = q ^ ((row>>1)&3); global_load_lds writes linearly so the
// inverse permutation is applied to the per-lane GLOBAL source address.
// C = A[M,K] @ Bt[N,K]^T.  A as Ah/Al [M][K], B as Bh/Bl [N][K], f16,
// value = h + l/4096.
// MODE 0: Ch/Cl = split(relu(C+bias))
// MODE 1: Ch/Cl = split(C+bias)
// MODE 2: split-K partial: Cf[(bz*M + row)*N + col] = C   (no bias; grid.z
//         = KSPLIT segments of ntseg tiles each; finalized by k_zfin)
// MODE 3: distance epilogue d = Z2[m] + C2[n] - 2*C; packed atomicMin(best)
template <int MODE>
__global__ __launch_bounds__(256, 2)
void k_gemm8(const _Float16* __restrict__ Ah, const _Float16* __restrict__ Al,
             const _Float16* __restrict__ Bh, const _Float16* __restrict__ Bl,
             const float* __restrict__ bias,
             _Float16* __restrict__ Ch, _Float16* __restrict__ Cl,
             float* __restrict__ Cf,
             const float* __restrict__ Z2, const float* __restrict__ C2,
             unsigned long long* __restrict__ best,
             int M, int N, int K, int ntseg) {
    constexpr int BUF = 16384;                 // f16 per buffer = 32 KB
    // per buffer: Ah @0 (128x32), Al @4096, Bh @8192, Bl @12288
    __shared__ __align__(16) _Float16 lds[2 * BUF];   // 64 KB

    const int tid  = threadIdx.x;
    const int w    = tid >> 6;
    const int l    = tid & 63;
    const int wm   = w >> 1, wn = w & 1;       // 2Mx2N wave grid
    const int quad = l >> 4, lcol = l & 15;
    const long m0 = (long)blockIdx.y * 128;
    const long n0 = (long)blockIdx.x * 128;
    const int kbase = (int)blockIdx.z * ntseg * 32;   // split-K (MODE 2)

    // Swizzled per-lane read offset (f16 units) within a matrix segment.
    // row = rb + lcol (rb % 16 == 0) -> (row>>1)&3 == (l>>1)&3.
    const int lidx = lcol * 32 + ((quad ^ ((l >> 1) & 3)) * 8);

    // Staging: wave w stages segment w (8 KB = 128 rows x 32 f16, 8 instrs
    // of 16 rows).  Lane covers 16 B: row16 = l>>2, phys k-slot = l&3,
    // logical k-slot = (l&3) ^ ((l>>3)&3)  (inverse of the read swizzle;
    // (row>>1)&3 == (l>>3)&3 since row = u*16 + (l>>2)).
    const _Float16* gsrc; long rbase;
    if      (w == 0) { gsrc = Ah; rbase = m0; }
    else if (w == 1) { gsrc = Al; rbase = m0; }
    else if (w == 2) { gsrc = Bh; rbase = n0; }
    else             { gsrc = Bl; rbase = n0; }
    const int grow = l >> 2;
    const int kq8  = (((l & 3) ^ ((l >> 3) & 3)) << 3);
    const _Float16* gbase = gsrc + (size_t)(rbase + grow) * K + kq8 + kbase;
    const int wseg = w * 4096;                 // per-wave LDS segment (f16)

    f32x4 acc_h[4][4], acc_x[4][4];
#pragma unroll
    for (int i = 0; i < 4; i++)
#pragma unroll
        for (int j = 0; j < 4; j++) {
            acc_h[i][j] = (f32x4){0.f, 0.f, 0.f, 0.f};
            acc_x[i][j] = (f32x4){0.f, 0.f, 0.f, 0.f};
        }

#define STAGE(bi, koff) do { \
        _Float16* d = lds + (bi) * BUF + wseg; \
        const _Float16* g = gbase + (koff); \
        gload_lds16(g,                      d);        \
        gload_lds16(g + (size_t)16  * K,    d + 512);  \
        gload_lds16(g + (size_t)32  * K,    d + 1024); \
        gload_lds16(g + (size_t)48  * K,    d + 1536); \
        gload_lds16(g + (size_t)64  * K,    d + 2048); \
        gload_lds16(g + (size_t)80  * K,    d + 2560); \
        gload_lds16(g + (size_t)96  * K,    d + 3072); \
        gload_lds16(g + (size_t)112 * K,    d + 3584); } while (0)

    // ---- prologue: stage tile 0 -> buf0 ----
    STAGE(0, 0);
    asm volatile("s_waitcnt vmcnt(0)" ::: "memory");
    __builtin_amdgcn_s_barrier();

#define LDA8(fi) do { \
        fa_h[fi] = *(const f16x8*)(sAh_ + (wm * 64 + (fi) * 16) * 32 + lidx); \
        fa_l[fi] = *(const f16x8*)(sAl_ + (wm * 64 + (fi) * 16) * 32 + lidx); } while (0)
#define LDB8(fj) do { \
        fb_h[fj] = *(const f16x8*)(sBh_ + (wn * 64 + (fj) * 16) * 32 + lidx); \
        fb_l[fj] = *(const f16x8*)(sBl_ + (wn * 64 + (fj) * 16) * 32 + lidx); } while (0)
#define MM3(fi, fj) do { \
        acc_h[fi][fj] = __builtin_amdgcn_mfma_f32_16x16x32_f16(fa_h[fi], fb_h[fj], acc_h[fi][fj], 0, 0, 0); \
        acc_x[fi][fj] = __builtin_amdgcn_mfma_f32_16x16x32_f16(fa_h[fi], fb_l[fj], acc_x[fi][fj], 0, 0, 0); \
        acc_x[fi][fj] = __builtin_amdgcn_mfma_f32_16x16x32_f16(fa_l[fi], fb_h[fj], acc_x[fi][fj], 0, 0, 0); } while (0)

    for (int t = 0; t < ntseg; ++t) {
        const _Float16* buf = lds + (t & 1) * BUF;
        const _Float16* sAh_ = buf;
        const _Float16* sAl_ = buf + 4096;
        const _Float16* sBh_ = buf + 8192;
        const _Float16* sBl_ = buf + 12288;
        const bool st = (t + 1) < ntseg;
        f16x8 fa_h[4], fa_l[4], fb_h[4], fb_l[4];

        // Stage tile t+1 first: the whole MFMA cluster hides its latency.
        if (st) STAGE((t + 1) & 1, 32);

        // Frag reads; first-quadrant reads lead so MFMA starts on counted
        // lgkmcnt while later reads are still in flight.
        LDA8(0); LDA8(1); LDB8(0); LDB8(1);
        LDA8(2); LDA8(3); LDB8(2); LDB8(3);

        __builtin_amdgcn_s_setprio(1);
        MM3(0, 0); MM3(0, 1); MM3(1, 0); MM3(1, 1);
        MM3(0, 2); MM3(0, 3); MM3(1, 2); MM3(1, 3);
        MM3(2, 0); MM3(2, 1); MM3(3, 0); MM3(3, 1);
        MM3(2, 2); MM3(2, 3); MM3(3, 2); MM3(3, 3);
        __builtin_amdgcn_s_setprio(0);

        // Boundary: tile t+1's stages (issued a full MFMA cluster ago).
        if (st) asm volatile("s_waitcnt vmcnt(0)" ::: "memory");
        __builtin_amdgcn_s_barrier();

        gbase += 32;
    }
#undef STAGE
#undef LDA8
#undef LDB8
#undef MM3

    if (MODE == 0 || MODE == 1) {
#pragma unroll
        for (int fj = 0; fj < 4; fj++) {
            const long col = n0 + wn * 64 + fj * 16 + lcol;
            const float bv = bias[col];
#pragma unroll
            for (int fi = 0; fi < 4; fi++) {
#pragma unroll
                for (int r = 0; r < 4; r++) {
                    const long row = m0 + wm * 64 + fi * 16 + quad * 4 + r;
                    float v = (acc_h[fi][fj][r] + INV4096 * acc_x[fi][fj][r]) + bv;
                    if (MODE == 0) v = fmaxf(v, 0.0f);
                    Split s = splitf(v);
                    const size_t o = (size_t)row * N + col;
                    Ch[o] = s.h; Cl[o] = s.l;
                }
            }
        }
    } else if (MODE == 2) {
        // split-K partial (fp32, no bias); unique (bz,row,col) per thread.
        const size_t pbase = (size_t)blockIdx.z * M * N;
#pragma unroll
        for (int fj = 0; fj < 4; fj++) {
            const long col = n0 + wn * 64 + fj * 16 + lcol;
#pragma unroll
            for (int fi = 0; fi < 4; fi++) {
#pragma unroll
                for (int r = 0; r < 4; r++) {
                    const long row = m0 + wm * 64 + fi * 16 + quad * 4 + r;
                    float v = acc_h[fi][fj][r] + INV4096 * acc_x[fi][fj][r];
                    Cf[pbase + (size_t)row * N + col] = v;
                }
            }
        }
    } else {
        float cc2[4];
#pragma unroll
        for (int fj = 0; fj < 4; fj++)
            cc2[fj] = C2[n0 + wn * 64 + fj * 16 + lcol];
#pragma unroll
        for (int fi = 0; fi < 4; fi++) {
#pragma unroll
            for (int r = 0; r < 4; r++) {
                const long row = m0 + wm * 64 + fi * 16 + quad * 4 + r;
                const float zz = Z2[row];
                float dmin = 3.4e38f; int didx = 0x7FFFFFFF;
#pragma unroll
                for (int fj = 0; fj < 4; fj++) {
                    float accv = acc_h[fi][fj][r] + INV4096 * acc_x[fi][fj][r];
                    int col = (int)(n0 + wn * 64 + fj * 16 + lcol);
                    float d = (zz + cc2[fj]) - 2.0f * accv;
                    if (d < dmin || (d == dmin && col < didx)) { dmin = d; didx = col; }
                }
#pragma unroll
                for (int off = 1; off < 16; off <<= 1) {
                    float ov = __shfl_xor(dmin, off, 64);
                    int   oi = __shfl_xor(didx, off, 64);
                    if (ov < dmin || (ov == dmin && oi < didx)) { dmin = ov; didx = oi; }
                }
                if (lcol == 0) {
                    unsigned long long pk =
                        ((unsigned long long)__float_as_uint(dmin) << 32) |
                        (unsigned long long)(unsigned)didx;
                    atomicMin(best + row, pk);
                }
            }
        }
    }
}

// ---------------------------------------------------------------------------
// Finalize z: sum KSPLIT split-K partials + bias, emit residual split
// (zH, zL) and row sq-norm z2.  One block per row, 64 threads (DZ=256).
__global__ void k_zfin(const float* __restrict__ zP, const float* __restrict__ b3,
                       _Float16* __restrict__ zH, _Float16* __restrict__ zL,
                       float* __restrict__ z2, int M) {
    const int row = blockIdx.x;
    const int t = threadIdx.x;                 // 64 lanes, 4 cols each
    float4 s = {0.f, 0.f, 0.f, 0.f};
#pragma unroll
    for (int ks = 0; ks < KSPLIT; ks++) {
        float4 v = *(const float4*)(zP + ((size_t)ks * M + row) * DZ + t * 4);
        s.x += v.x; s.y += v.y; s.z += v.z; s.w += v.w;
    }
    float4 bv = *(const float4*)(b3 + t * 4);
    s.x += bv.x; s.y += bv.y; s.z += bv.z; s.w += bv.w;
    Split p0 = splitf(s.x), p1 = splitf(s.y), p2 = splitf(s.z), p3 = splitf(s.w);
    f16x4 hv, lv;
    hv[0] = p0.h; hv[1] = p1.h; hv[2] = p2.h; hv[3] = p3.h;
    lv[0] = p0.l; lv[1] = p1.l; lv[2] = p2.l; lv[3] = p3.l;
    *(f16x4*)(zH + (size_t)row * DZ + t * 4) = hv;
    *(f16x4*)(zL + (size_t)row * DZ + t * 4) = lv;
    float ssq = s.x * s.x + s.y * s.y + s.z * s.z + s.w * s.w;
#pragma unroll
    for (int off = 32; off > 0; off >>= 1) ssq += __shfl_down(ssq, off, 64);
    if (t == 0) z2[row] = ssq;
}

// ---------------------------------------------------------------------------
__global__ void k_row_sq_norms(const float* __restrict__ X, float* __restrict__ out,
                               int ncols, int nrows) {
    const int wave = threadIdx.x >> 6;
    const int lane = threadIdx.x & 63;
    const long row = (long)blockIdx.x * 4 + wave;
    if (row >= nrows) return;
    const float* p = X + row * (long)ncols;
    float s = 0.0f;
    for (int c = lane * 4; c < ncols; c += 256) {
        float4 v = *(const float4*)(p + c);
        s += v.x * v.x + v.y * v.y + v.z * v.z + v.w * v.w;
    }
#pragma unroll
    for (int off = 32; off > 0; off >>= 1) s += __shfl_down(s, off, 64);
    if (lane == 0) out[row] = s;
}

__global__ void k_loss(const unsigned long long* __restrict__ best,
                       float* __restrict__ out) {
    __shared__ float red[256];
    float s = 0.0f;
    for (int i = threadIdx.x; i < NROWS; i += 256)
        s += __uint_as_float((unsigned)(best[i] >> 32));
    red[threadIdx.x] = s;
    __syncthreads();
    for (int st = 128; st > 0; st >>= 1) {
        if (threadIdx.x < st) red[threadIdx.x] += red[threadIdx.x + st];
        __syncthreads();
    }
    if (threadIdx.x == 0) out[(size_t)NROWS * DZ] = 2.0f * red[0];
}

__global__ void k_output(const float* __restrict__ CB,
                         const unsigned long long* __restrict__ best,
                         float* __restrict__ out) {
    const long n = blockIdx.x;
    const int t = threadIdx.x;      // 64 threads
    const int wd = (int)(unsigned)(best[n] & 0xFFFFFFFFULL);
    float4 v = *(const float4*)(CB + (size_t)wd * DZ + t * 4);
    *(float4*)(out + n * (size_t)DZ + t * 4) = v;
}

// ---------------------------------------------------------------------------
extern "C" void kernel_launch(void* const* d_in, const int* in_sizes, int n_in,
                              void* d_out, int out_size, void* d_ws, size_t ws_size,
                              hipStream_t stream) {
    const float* x  = (const float*)d_in[0];
    const float* W1 = (const float*)d_in[1];
    const float* b1 = (const float*)d_in[2];
    const float* W2 = (const float*)d_in[3];
    const float* b2 = (const float*)d_in[4];
    const float* W3 = (const float*)d_in[5];
    const float* b3 = (const float*)d_in[6];
    const float* cb = (const float*)d_in[7];
    float* out = (float*)d_out;

    // ---- workspace carve-up (bytes, 256-aligned) ----
    char* base = (char*)d_ws;
    size_t off = 0;
    auto alloc = [&](size_t bytes) -> void* {
        void* p = base + off;
        off = (off + bytes + 255) & ~(size_t)255;
        return p;
    };
    // fixed region: weights, codebook, z, norms, best
    _Float16* W1tH = (_Float16*)alloc((size_t)DH * DIN * 2);
    _Float16* W1tL = (_Float16*)alloc((size_t)DH * DIN * 2);
    _Float16* W2tH = (_Float16*)alloc((size_t)DH * DH * 2);
    _Float16* W2tL = (_Float16*)alloc((size_t)DH * DH * 2);
    _Float16* W3tH = (_Float16*)alloc((size_t)DZ * DH * 2);
    _Float16* W3tL = (_Float16*)alloc((size_t)DZ * DH * 2);
    _Float16* cbH  = (_Float16*)alloc((size_t)KCB * DZ * 2);
    _Float16* cbL  = (_Float16*)alloc((size_t)KCB * DZ * 2);
    _Float16* zH   = (_Float16*)alloc((size_t)NROWS * DZ * 2);
    _Float16* zL   = (_Float16*)alloc((size_t)NROWS * DZ * 2);
    float*    z2   = (float*)alloc((size_t)NROWS * 4);
    float*    c2   = (float*)alloc((size_t)KCB * 4);
    unsigned long long* best = (unsigned long long*)alloc((size_t)NROWS * 8);

    // chunk buffers: x split (4 KB/row) + h1/h2 splits (16 KB/row each)
    // + split-K z partials (KSPLIT * DZ * 4 = 8 KB/row)
    size_t rem = (ws_size > off) ? (ws_size - off) : 0;
    size_t perrow = (size_t)DIN * 2 * 2 + (size_t)DH * 2 * 4 + (size_t)KSPLIT * DZ * 4;
    size_t rc = rem / perrow;
    rc = (rc / 256) * 256;
    if (rc > NROWS) rc = NROWS;
    if (rc < 256)   rc = 256;
    _Float16* xcH = (_Float16*)alloc((size_t)rc * DIN * 2);
    _Float16* xcL = (_Float16*)alloc((size_t)rc * DIN * 2);
    _Float16* h1H = (_Float16*)alloc((size_t)rc * DH * 2);
    _Float16* h1L = (_Float16*)alloc((size_t)rc * DH * 2);
    _Float16* h2H = (_Float16*)alloc((size_t)rc * DH * 2);
    _Float16* h2L = (_Float16*)alloc((size_t)rc * DH * 2);
    float*    zP  = (float*)alloc((size_t)KSPLIT * rc * DZ * 4);

    // ---- one-time conversions ----
    k_init_best<<<(NROWS + 255) / 256, 256, 0, stream>>>(best);
    k_esplit<<<(unsigned)((size_t)KCB * DZ / 1024), 256, 0, stream>>>(
        cb, cbH, cbL, (size_t)KCB * DZ);
    k_tsplit<<<dim3(DIN / 32, DH / 32), dim3(32, 8), 0, stream>>>(W1, W1tH, W1tL, DIN, DH);
    k_tsplit<<<dim3(DH / 32, DH / 32),  dim3(32, 8), 0, stream>>>(W2, W2tH, W2tL, DH, DH);
    k_tsplit<<<dim3(DH / 32, DZ / 32),  dim3(32, 8), 0, stream>>>(W3, W3tH, W3tL, DH, DZ);

    // ---- MLP (chunked over rows; rows always a multiple of 256) ----
    for (size_t r0 = 0; r0 < NROWS; r0 += rc) {
        size_t rows = NROWS - r0;
        if (rows > rc) rows = rc;
        // x chunk -> split f16
        k_esplit<<<(unsigned)(rows * DIN / 1024), 256, 0, stream>>>(
            x + r0 * DIN, xcH, xcL, rows * DIN);
        // h1 = relu(x @ W1 + b1)
        k_gemm8<0><<<dim3(DH / 128, rows / 128), 256, 0, stream>>>(
            xcH, xcL, W1tH, W1tL, b1, h1H, h1L, nullptr,
            nullptr, nullptr, nullptr, (int)rows, DH, DIN, DIN / 32);
        // h2 = h1 @ W2 + b2
        k_gemm8<1><<<dim3(DH / 128, rows / 128), 256, 0, stream>>>(
            h1H, h1L, W2tH, W2tL, b2, h2H, h2L, nullptr,
            nullptr, nullptr, nullptr, (int)rows, DH, DH, DH / 32);
        // z partials = h2 @ W3  (split-K=8, pipelined kernel; N=256)
        k_gemm8<2><<<dim3(DZ / 128, rows / 128, KSPLIT), 256, 0, stream>>>(
            h2H, h2L, W3tH, W3tL, nullptr, nullptr, nullptr, zP,
            nullptr, nullptr, nullptr, (int)rows, DZ, DH, DH / 32 / KSPLIT);
        // finalize: sum partials + b3 -> zH/zL (residual) + z2 row norms
        k_zfin<<<(unsigned)rows, 64, 0, stream>>>(
            zP, b3, zH + r0 * DZ, zL + r0 * DZ, z2 + r0, (int)rows);
    }

    // ---- codebook norms + distance/argmin + outputs ----
    k_row_sq_norms<<<KCB / 4, 256, 0, stream>>>(cb, c2, DZ, KCB);

    // distance + argmin  [3-stream, K=256 -> 8 tiles]
    k_gemm8<3><<<dim3(KCB / 128, NROWS / 128), 256, 0, stream>>>(
        zH, zL, cbH, cbL, nullptr, nullptr, nullptr, nullptr,
        z2, c2, best, NROWS, KCB, DZ, DZ / 32);

    k_loss<<<1, 256, 0, stream>>>(best, out);
    k_output<<<NROWS, 64, 0, stream>>>(cb, best, out);
}